// Round 1
// 467.875 us; speedup vs baseline: 1.1401x; 1.1401x over previous
//
#include <hip/hip_runtime.h>
#include <math.h>

#define NROW 16384   // B*N rows
#define NCOL 4096
#define CDIM 256
#define DKDIM 64
#define SCALE 0.125f // DK^-0.5

typedef float v4f __attribute__((ext_vector_type(4)));
typedef __attribute__((ext_vector_type(8))) short short8v;  // 8 bf16 = 4 VGPR
typedef __attribute__((ext_vector_type(4))) float f32x4;

// ---- monotone float<->u32 key helpers (unsigned compare == float compare) ----
__device__ __forceinline__ unsigned mono(float v) {
  unsigned u = __float_as_uint(v);
  unsigned s = (unsigned)(((int)u) >> 31);
  return u ^ (s | 0x80000000u);
}
__device__ __forceinline__ float unmono(unsigned k) {
  unsigned u = (k & 0x80000000u) ? (k ^ 0x80000000u) : ~k;
  return __uint_as_float(u);
}
__device__ __forceinline__ unsigned short f2bf(float f) {  // RNE bf16
  unsigned u = __float_as_uint(f);
  u += 0x7FFFu + ((u >> 16) & 1u);
  return (unsigned short)(u >> 16);
}
__device__ __forceinline__ unsigned umaxu(unsigned a, unsigned b) { return a > b ? a : b; }

// ---- top-8 maintenance on packed keys (port of the proven s_topk logic) ----
__device__ __forceinline__ void ins8(unsigned tk[8], unsigned& tmin, int& tmpos, unsigned v) {
  #pragma unroll
  for (int j = 0; j < 8; ++j) if (j == tmpos) tk[j] = v;
  tmin = tk[0]; tmpos = 0;
  #pragma unroll
  for (int j = 1; j < 8; ++j) if (tk[j] < tmin) { tmin = tk[j]; tmpos = j; }
}
__device__ __forceinline__ unsigned umax8(const unsigned kv[8]) {
  unsigned a = umaxu(umaxu(kv[0], kv[1]), umaxu(kv[2], kv[3]));
  unsigned b = umaxu(umaxu(kv[4], kv[5]), umaxu(kv[6], kv[7]));
  return umaxu(a, b);
}
__device__ __forceinline__ void seed8(const unsigned* __restrict__ sp,
                                      unsigned tk[8], unsigned& tmin, int& tmpos) {
  uint4 ka = *(const uint4*)(sp);
  uint4 kb = *(const uint4*)(sp + 4);
  tk[0] = ka.x; tk[1] = ka.y; tk[2] = ka.z; tk[3] = ka.w;
  tk[4] = kb.x; tk[5] = kb.y; tk[6] = kb.z; tk[7] = kb.w;
  tmin = tk[0]; tmpos = 0;
  #pragma unroll
  for (int j = 1; j < 8; ++j) if (tk[j] < tmin) { tmin = tk[j]; tmpos = j; }
}
__device__ __forceinline__ void scan8(const unsigned* __restrict__ sp,
                                      unsigned tk[8], unsigned& tmin, int& tmpos) {
  uint4 ka = *(const uint4*)(sp);
  uint4 kb = *(const uint4*)(sp + 4);
  unsigned kv[8] = {ka.x, ka.y, ka.z, ka.w, kb.x, kb.y, kb.z, kb.w};
  unsigned gm = umax8(kv);
  #pragma unroll
  for (int pass = 0; pass < 2; ++pass) {
    if (__any(gm > tmin)) {            // wave-uniform branch
      if (gm > tmin) {                 // per-lane insert (keys unique: col in low bits)
        ins8(tk, tmin, tmpos, gm);
        #pragma unroll
        for (int j = 0; j < 8; ++j) if (kv[j] == gm) kv[j] = 0u;
      }
      gm = umax8(kv);
    }
  }
  if (__any(gm > tmin)) {              // rare: >=3 qualifiers in this group
    #pragma unroll
    for (int j = 0; j < 8; ++j) if (kv[j] > tmin) ins8(tk, tmin, tmpos, kv[j]);
  }
}

// ---------------- Kernel 1: fused Q/K projection (fp32 + bf16 row-major) ----
__global__ __launch_bounds__(512, 2) void qk_proj(
    const float* __restrict__ x, const float* __restrict__ Wq,
    const float* __restrict__ Wk, float* __restrict__ Qt,
    float* __restrict__ Kt, unsigned short* __restrict__ Qh,
    unsigned short* __restrict__ Kh) {
  __shared__ float4 xs4[64][65];  // row stride 65 f4-units -> bank-group spread
  const int t = threadIdx.x;
  const int rb = blockIdx.x;      // 256 blocks of 64 rows
  {
    const float4* xg = (const float4*)(x + (size_t)rb * 64 * CDIM);
    #pragma unroll
    for (int i = 0; i < 8; ++i) {
      int idx = i * 512 + t;      // 0..4095
      xs4[idx >> 6][idx & 63] = xg[idx];
    }
  }
  __syncthreads();

  const int lane = t & 63;
  const int wu = __builtin_amdgcn_readfirstlane(t >> 6);  // wave id, uniform
  const int proj = wu >> 2;
  const int chunk = wu & 3;       // d-chunk: d = chunk*16 .. +15
  const float* __restrict__ Wp = proj ? Wk : Wq;

  float acc[16];
  #pragma unroll
  for (int j = 0; j < 16; ++j) acc[j] = 0.f;

  #pragma unroll 4
  for (int cs = 0; cs < 64; ++cs) {        // 4 c's per step
    float4 xv = xs4[lane][cs];
    const float xc[4] = {xv.x, xv.y, xv.z, xv.w};
    #pragma unroll
    for (int i = 0; i < 4; ++i) {
      const float4* __restrict__ w4 =
          (const float4*)(Wp + (size_t)(cs * 4 + i) * DKDIM + chunk * 16);
      float4 wa = w4[0], wb = w4[1], wc = w4[2], wd = w4[3];
      float xi = xc[i];
      acc[0]  = fmaf(xi, wa.x, acc[0]);  acc[1]  = fmaf(xi, wa.y, acc[1]);
      acc[2]  = fmaf(xi, wa.z, acc[2]);  acc[3]  = fmaf(xi, wa.w, acc[3]);
      acc[4]  = fmaf(xi, wb.x, acc[4]);  acc[5]  = fmaf(xi, wb.y, acc[5]);
      acc[6]  = fmaf(xi, wb.z, acc[6]);  acc[7]  = fmaf(xi, wb.w, acc[7]);
      acc[8]  = fmaf(xi, wc.x, acc[8]);  acc[9]  = fmaf(xi, wc.y, acc[9]);
      acc[10] = fmaf(xi, wc.z, acc[10]); acc[11] = fmaf(xi, wc.w, acc[11]);
      acc[12] = fmaf(xi, wd.x, acc[12]); acc[13] = fmaf(xi, wd.y, acc[13]);
      acc[14] = fmaf(xi, wd.z, acc[14]); acc[15] = fmaf(xi, wd.w, acc[15]);
    }
  }

  const int gr = rb * 64 + lane;  // global row
  // fp32 row-major [row][64] (exact-recompute source in finalize)
  float* Of = (proj ? Kt : Qt) + (size_t)gr * 64 + chunk * 16;
  #pragma unroll
  for (int i = 0; i < 4; ++i) {
    float4 o = {acc[4 * i], acc[4 * i + 1], acc[4 * i + 2], acc[4 * i + 3]};
    ((float4*)Of)[i] = o;
  }
  // bf16 row-major [row][64] (MFMA operand source in s_cand)
  unsigned short* Oh = (proj ? Kh : Qh) + (size_t)gr * 64 + chunk * 16;
  unsigned hp[8];
  #pragma unroll
  for (int i = 0; i < 8; ++i)
    hp[i] = (unsigned)f2bf(acc[2 * i]) | ((unsigned)f2bf(acc[2 * i + 1]) << 16);
  uint4 h0 = {hp[0], hp[1], hp[2], hp[3]};
  uint4 h1 = {hp[4], hp[5], hp[6], hp[7]};
  ((uint4*)Oh)[0] = h0;
  ((uint4*)Oh)[1] = h1;
}

// ---------------- Kernel 2: MFMA S-tiles + per-row approx top-8 per chunk ----
// Same 2048-block geometry/XCD swizzle as before. Each wave owns 16 rows x
// 512 cols: per 16x16 tile, 2x mfma_f32_16x16x32_bf16 (k-halves; any k-perm
// error in the assumed fragment layout cancels since A and B use the same
// mapping). Accums are packed to (monotone-value|col) u32 keys in wave-private
// LDS; 4 lanes/row run the proven group-of-8 insert scan. No __syncthreads.
__global__ __launch_bounds__(256, 4) void s_cand(
    const unsigned short* __restrict__ Qh, const unsigned short* __restrict__ Kh,
    float* __restrict__ out, unsigned* __restrict__ wsk) {
  __shared__ unsigned keys[4][16 * 132];  // 33792 B -> 4 blocks/CU
  const int t = threadIdx.x;
  const int lane = t & 63;
  const int w = __builtin_amdgcn_readfirstlane(t >> 6);
  const int f = blockIdx.x;        // 0..2047, XCD swizzle decode
  const int xs = f & 7;
  const int i5 = f >> 3;
  const int combo = xs * 4 + (i5 >> 6);   // 0..31
  const int rbL = i5 & 63;
  const int b = combo >> 3;        // batch
  const int chunk = combo & 7;     // col-chunk of 512
  const int rb = b * 64 + rbL;

  const int l15 = lane & 15, lk = lane >> 4;
  // A-fragments: my 16 Q rows, loaded once. row = lane&15, k = (lane>>4)*8+j.
  const int rowg = (b << 12) + rbL * 64 + w * 16 + l15;
  const short8v a0 = *(const short8v*)(Qh + (size_t)rowg * 64 + lk * 8);
  const short8v a1 = *(const short8v*)(Qh + (size_t)rowg * 64 + lk * 8 + 32);

  // zero-fill my 64x512 output region (drains in background under compute)
  {
    v4f z = {0.f, 0.f, 0.f, 0.f};
    v4f* o4 = (v4f*)out + (size_t)rb * 64 * 1024 + chunk * 128;
    #pragma unroll 8
    for (int i = 0; i < 32; ++i) {
      int g = i * 256 + t;         // 0..8191: 64 rows x 128 f4
      __builtin_nontemporal_store(z, &o4[(size_t)(g >> 7) * 1024 + (g & 127)]);
    }
  }

  unsigned* krow = keys[w];
  const int myrow = lane >> 2, q = lane & 3;   // scan: 4 lanes per row
  const unsigned short* Kb = Kh + ((size_t)(b << 12)) * 64;

  unsigned tk[8]; unsigned tmin; int tmpos;

  #pragma unroll 1
  for (int qt = 0; qt < 4; ++qt) {   // 4 quarters of 128 cols
    const int colbase = chunk * 512 + qt * 128;
    #pragma unroll
    for (int ct = 0; ct < 8; ++ct) { // 8 col-tiles of 16
      const int col = colbase + ct * 16 + l15;
      const unsigned short* kp = Kb + (size_t)col * 64 + lk * 8;
      const short8v b0 = *(const short8v*)(kp);        // B: col=lane&15, k-half 0
      const short8v b1 = *(const short8v*)(kp + 32);   // k-half 1
      f32x4 acc = {0.f, 0.f, 0.f, 0.f};
      acc = __builtin_amdgcn_mfma_f32_16x16x32_bf16(a0, b0, acc, 0, 0, 0);
      acc = __builtin_amdgcn_mfma_f32_16x16x32_bf16(a1, b1, acc, 0, 0, 0);
      // C/D: col=lane&15, row=(lane>>4)*4+i (m89-verified). Pack to keys.
      #pragma unroll
      for (int i = 0; i < 4; ++i) {
        unsigned kk = (mono(acc[i]) & 0xFFFFF000u) | (unsigned)col;
        krow[(lk * 4 + i) * 132 + ct * 16 + l15] = kk;  // stride 132: 2-way banks
      }
    }
    // scan my 32 cols of this quarter (contiguous sub-span q*32..q*32+31)
    const unsigned* sp = krow + myrow * 132 + q * 32;
    if (qt == 0) {
      seed8(sp, tk, tmin, tmpos);
      scan8(sp + 8, tk, tmin, tmpos);
      scan8(sp + 16, tk, tmin, tmpos);
      scan8(sp + 24, tk, tmin, tmpos);
    } else {
      #pragma unroll
      for (int g = 0; g < 4; ++g) scan8(sp + 8 * g, tk, tmin, tmpos);
    }
  }

  // wave-internal merge: 4 lanes x 8 keys -> per-row top-8 (reuse LDS, no barrier:
  // same-wave DS ops are in-order and compiler inserts lgkmcnt waits)
  {
    uint4 s0 = {tk[0], tk[1], tk[2], tk[3]};
    uint4 s1 = {tk[4], tk[5], tk[6], tk[7]};
    uint4* mp4 = (uint4*)(krow + myrow * 36 + q * 8);
    mp4[0] = s0; mp4[1] = s1;
  }
  if (lane < 16) {
    const unsigned* mp = krow + lane * 36;
    unsigned mt[8]; unsigned mmin; int mmpos;
    seed8(mp, mt, mmin, mmpos);
    scan8(mp + 8, mt, mmin, mmpos);
    scan8(mp + 16, mt, mmin, mmpos);
    scan8(mp + 24, mt, mmin, mmpos);
    const int grow = (b << 12) + rbL * 64 + w * 16 + lane;
    uint4 o0 = {mt[0], mt[1], mt[2], mt[3]};
    uint4 o1 = {mt[4], mt[5], mt[6], mt[7]};
    uint4* wp = (uint4*)(wsk + (size_t)grow * 64 + chunk * 8);
    wp[0] = o0; wp[1] = o1;
  }
}

// ---------------- Kernel 3: exact recompute of 64 candidates + softmax ------
// 1 wave per row; lane = candidate. Exact fp32 dot in the SAME sequential fma
// order as the previous kernel (bitwise-identical scores), then 8x shuffle-max
// extraction on full-precision monotone keys, identical __expf softmax, scatter.
__global__ __launch_bounds__(256) void finalize(
    const float* __restrict__ Qt, const float* __restrict__ Kt,
    const unsigned* __restrict__ wsk, float* __restrict__ out) {
  const int t = threadIdx.x;
  const int lane = t & 63;
  const int w = t >> 6;
  const int row = blockIdx.x * 4 + w;
  const int b = row >> 12;
  const unsigned key = wsk[(size_t)row * 64 + lane];
  const int col = (int)(key & 0xFFFu);   // batch-local column
  const float4* Kp = (const float4*)(Kt + ((size_t)((b << 12) + col)) * 64);
  const float4* Qp = (const float4*)(Qt + (size_t)row * 64);  // uniform -> s_load
  float s = 0.f;
  #pragma unroll
  for (int g = 0; g < 16; ++g) {
    float4 qf = Qp[g];
    float4 kf = Kp[g];
    s = fmaf(qf.x, kf.x, s);
    s = fmaf(qf.y, kf.y, s);
    s = fmaf(qf.z, kf.z, s);
    s = fmaf(qf.w, kf.w, s);
  }
  unsigned kx = mono(s);  // full precision: exact ordering
  float vals[8]; int cols[8];
  #pragma unroll
  for (int it = 0; it < 8; ++it) {
    unsigned m = kx;
    #pragma unroll
    for (int d = 1; d < 64; d <<= 1) m = umaxu(m, (unsigned)__shfl_xor((int)m, d, 64));
    unsigned long long win = __ballot(kx == m);
    int wl = (int)__ffsll(win) - 1;
    cols[it] = __shfl(col, wl, 64);
    vals[it] = unmono(m);
    if (lane == wl) kx = 0u;   // exclude winner
  }
  float e[8], sum = 0.f;
  #pragma unroll
  for (int it = 0; it < 8; ++it) { e[it] = __expf((vals[it] - vals[0]) * SCALE); sum += e[it]; }
  float inv = 1.f / sum;
  if (lane == 0) {
    float* orow = out + ((size_t)row << 12);
    #pragma unroll
    for (int it = 0; it < 8; ++it) orow[cols[it]] = e[it] * inv;
  }
}

extern "C" void kernel_launch(void* const* d_in, const int* in_sizes, int n_in,
                              void* d_out, int out_size, void* d_ws, size_t ws_size,
                              hipStream_t stream) {
  const float* x  = (const float*)d_in[0];
  const float* Wq = (const float*)d_in[1];
  const float* Wk = (const float*)d_in[2];
  float* out = (float*)d_out;

  char* ws = (char*)d_ws;                       // 16 MB total, same as before
  float* Qt = (float*)ws;                       // 4 MB fp32 [row][64]
  float* Kt = (float*)(ws + ((size_t)4 << 20)); // 4 MB
  unsigned short* Qh = (unsigned short*)(ws + ((size_t)8 << 20));   // 2 MB bf16
  unsigned short* Kh = (unsigned short*)(ws + ((size_t)10 << 20));  // 2 MB
  unsigned* wsk = (unsigned*)(ws + ((size_t)12 << 20));             // 4 MB keys

  qk_proj<<<dim3(NROW / 64), 512, 0, stream>>>(x, Wq, Wk, Qt, Kt, Qh, Kh);
  s_cand<<<2048, 256, 0, stream>>>(Qh, Kh, out, wsk);
  finalize<<<NROW / 4, 256, 0, stream>>>(Qt, Kt, wsk, out);
}